// Round 1
// baseline (204272.839 us; speedup 1.0000x reference)
//
#include <hip/hip_runtime.h>

// Problem dims
constexpr int NB = 32;    // batch
constexpr int NT = 128;   // time
constexpr int NE = 256;   // embed
constexpr int NH = 256;   // hidden
constexpr int NC = 16;    // classes

__device__ __forceinline__ float sigmoidf_(float x) {
    return 1.f / (1.f + __expf(-x));
}
__device__ __forceinline__ float tanhf_(float x) {
    // clamp to avoid exp overflow -> NaN; tanh saturates anyway
    x = fminf(fmaxf(x, -15.f), 15.f);
    float e = __expf(-2.f * x);
    return (1.f - e) / (1.f + e);
}
__device__ __forceinline__ float dot4_(float4 a, float4 b) {
    return a.x * b.x + a.y * b.y + a.z * b.z + a.w * b.w;
}

// ---------------- Prologue 1: xp[t][b][j] = x[b][t][:] . W_in[j][:] + b_in[j]
__global__ __launch_bounds__(256) void k_lin_in(
    const float* __restrict__ x, const float* __restrict__ W_in,
    const float* __restrict__ b_in, float* __restrict__ xp) {
    const int tb = blockIdx.x;           // t*NB + b
    const int t = tb >> 5, b = tb & 31;
    const int tid = threadIdx.x;
    __shared__ __align__(16) float xl[NE];
    xl[tid] = x[(b * NT + t) * NE + tid];
    __syncthreads();
    const float* __restrict__ wr = W_in + tid * NE;
    float acc = b_in[tid];
#pragma unroll 8
    for (int k = 0; k < NE; k += 4)
        acc += dot4_(*(const float4*)(wr + k), *(const float4*)(xl + k));
    xp[tb * NH + tid] = acc;
}

// ---------------- Prologue 2: xw[t][b][0:3H] = xp . Wih^T + bih ; uax = xp . Ua^T + ub
__global__ __launch_bounds__(256) void k_proj(
    const float* __restrict__ xp, const float* __restrict__ Wih,
    const float* __restrict__ bih, const float* __restrict__ Ua,
    const float* __restrict__ ub, float* __restrict__ xw,
    float* __restrict__ uax) {
    const int tb = blockIdx.x;
    const int tid = threadIdx.x;
    __shared__ __align__(16) float xl[NH];
    xl[tid] = xp[tb * NH + tid];
    __syncthreads();
    const float* __restrict__ wr = Wih + tid * NH;
    const float* __restrict__ wz = Wih + (NH + tid) * NH;
    const float* __restrict__ wn = Wih + (2 * NH + tid) * NH;
    const float* __restrict__ wu = Ua + tid * NH;
    float ar = bih[tid], az = bih[NH + tid], an = bih[2 * NH + tid], au = ub[tid];
#pragma unroll 4
    for (int k = 0; k < NH; k += 4) {
        float4 xv = *(const float4*)(xl + k);
        ar += dot4_(*(const float4*)(wr + k), xv);
        az += dot4_(*(const float4*)(wz + k), xv);
        an += dot4_(*(const float4*)(wn + k), xv);
        au += dot4_(*(const float4*)(wu + k), xv);
    }
    float* xwp = xw + tb * (3 * NH);
    xwp[tid] = ar;
    xwp[NH + tid] = az;
    xwp[2 * NH + tid] = an;
    uax[tb * NH + tid] = au;
}

// ---------------- Main: one workgroup per batch element, fully independent.
__global__ __launch_bounds__(256) void k_main(
    const float* __restrict__ Whh, const float* __restrict__ bhh,
    const float* __restrict__ Wa, const float* __restrict__ ba,
    const float* __restrict__ va_w, const float* __restrict__ Wo,
    const float* __restrict__ bo, const float* __restrict__ xp,
    const float* __restrict__ xw, const float* __restrict__ uax,
    float* __restrict__ outs, float* __restrict__ out) {
    const int b = blockIdx.x;
    const int tid = threadIdx.x;
    const int lane = tid & 63, wid = tid >> 6;

    __shared__ __align__(16) float hbuf[2][NH];
    __shared__ float wsm[NT];
    __shared__ float scores[NT];
    __shared__ float red[4][8];
    __shared__ float redo[4 * NC];

    const float bhr = bhh[tid], bhz = bhh[NH + tid], bhn = bhh[2 * NH + tid];
    const float ba_j = ba[tid];
    const float va_j = va_w[tid];
    const float* __restrict__ wrh = Whh + tid * NH;
    const float* __restrict__ wzh = Whh + (NH + tid) * NH;
    const float* __restrict__ wnh = Whh + (2 * NH + tid) * NH;
    const float* __restrict__ wa = Wa + tid * NH;
    float* __restrict__ ob = outs + (size_t)b * NT * NH;

    hbuf[0][tid] = 0.f;
    __syncthreads();
    int cur = 0;

    for (int i = 0; i < NT; ++i) {
        // ---- sequential GRU chain over the prefix t = 0..i (carried hidden)
        for (int t = 0; t <= i; ++t) {
            const float* __restrict__ xwp = xw + (t * NB + b) * (3 * NH);
            const float xr = xwp[tid], xz = xwp[NH + tid], xn = xwp[2 * NH + tid];
            const float* __restrict__ hc = hbuf[cur];
            float accr = 0.f, accz = 0.f, accn = 0.f;
#pragma unroll 8
            for (int k = 0; k < NH; k += 4) {
                const float4 hv = *(const float4*)(hc + k);
                accr += dot4_(*(const float4*)(wrh + k), hv);
                accz += dot4_(*(const float4*)(wzh + k), hv);
                accn += dot4_(*(const float4*)(wnh + k), hv);
            }
            const float r = sigmoidf_(xr + accr + bhr);
            const float z = sigmoidf_(xz + accz + bhz);
            const float n = tanhf_(xn + r * (accn + bhn));
            const float hnew = (1.f - z) * n + z * hc[tid];
            hbuf[cur ^ 1][tid] = hnew;
            ob[t * NH + tid] = hnew;   // outs[t] for this outer step
            cur ^= 1;
            __syncthreads();
        }
        __threadfence_block();
        __syncthreads();

        // ---- attention scores: score[t] = va . tanh(Wa @ outs[t] + ba + uax[t])
        for (int t0 = 0; t0 <= i; t0 += 8) {
            float sacc[8] = {0, 0, 0, 0, 0, 0, 0, 0};
#pragma unroll 2
            for (int k = 0; k < NH; k += 4) {
                const float4 w4 = *(const float4*)(wa + k);
#pragma unroll
                for (int tt = 0; tt < 8; ++tt)
                    sacc[tt] += dot4_(w4, *(const float4*)(ob + (t0 + tt) * NH + k));
            }
#pragma unroll
            for (int tt = 0; tt < 8; ++tt) {
                const int t = t0 + tt;   // t <= 127 always (in-bounds); t > i masked later
                float sv = sacc[tt] + ba_j + uax[(t * NB + b) * NH + tid];
                float contrib = va_j * tanhf_(sv);
#pragma unroll
                for (int off = 32; off; off >>= 1) contrib += __shfl_xor(contrib, off);
                if (lane == 0) red[wid][tt] = contrib;
            }
            __syncthreads();
            if (tid < 8)
                scores[t0 + tid] = red[0][tid] + red[1][tid] + red[2][tid] + red[3][tid];
            __syncthreads();
        }

        // ---- softmax over t = 0..i (wave 0); va_b cancels in softmax
        if (tid < 64) {
            float s1 = (tid <= i) ? scores[tid] : -1e30f;
            float s2 = (64 + tid <= i) ? scores[64 + tid] : -1e30f;
            float m = fmaxf(s1, s2);
#pragma unroll
            for (int off = 32; off; off >>= 1) m = fmaxf(m, __shfl_xor(m, off));
            float e1 = (tid <= i) ? __expf(s1 - m) : 0.f;
            float e2 = (64 + tid <= i) ? __expf(s2 - m) : 0.f;
            float ssum = e1 + e2;
#pragma unroll
            for (int off = 32; off; off >>= 1) ssum += __shfl_xor(ssum, off);
            float inv = 1.f / ssum;
            wsm[tid] = e1 * inv;
            wsm[64 + tid] = e2 * inv;
        }
        __syncthreads();

        // ---- context = sum_t w[t] * xp[t][b][:]
        float cacc = 0.f;
        for (int t = 0; t <= i; ++t) cacc += wsm[t] * xp[(t * NB + b) * NH + tid];
        const float hl = hbuf[cur][tid];

        // ---- output head: logits = [h_last, context] @ Wo^T + bo, then sigmoid
        float p[NC];
#pragma unroll
        for (int c = 0; c < NC; ++c)
            p[c] = Wo[c * (2 * NH) + tid] * hl + Wo[c * (2 * NH) + NH + tid] * cacc;
#pragma unroll
        for (int c = 0; c < NC; ++c) {
            float v = p[c];
#pragma unroll
            for (int off = 32; off; off >>= 1) v += __shfl_xor(v, off);
            if (lane == 0) redo[wid * NC + c] = v;
        }
        __syncthreads();
        if (tid < NC) {
            float lg = redo[tid] + redo[NC + tid] + redo[2 * NC + tid] +
                       redo[3 * NC + tid] + bo[tid];
            out[(b * NT + i) * NC + tid] = sigmoidf_(lg);
        }
        __syncthreads();
    }
}

extern "C" void kernel_launch(void* const* d_in, const int* in_sizes, int n_in,
                              void* d_out, int out_size, void* d_ws, size_t ws_size,
                              hipStream_t stream) {
    (void)in_sizes; (void)n_in; (void)out_size; (void)ws_size;
    const float* x    = (const float*)d_in[0];
    const float* W_in = (const float*)d_in[1];
    const float* b_in = (const float*)d_in[2];
    const float* Wih  = (const float*)d_in[3];
    const float* bih  = (const float*)d_in[4];
    const float* Whh  = (const float*)d_in[5];
    const float* bhh  = (const float*)d_in[6];
    const float* Wa   = (const float*)d_in[7];
    const float* ba   = (const float*)d_in[8];
    const float* Ua   = (const float*)d_in[9];
    const float* ub   = (const float*)d_in[10];
    const float* va_w = (const float*)d_in[11];
    // d_in[12] = va_b: constant across t -> cancels in softmax, unused
    const float* Wo   = (const float*)d_in[13];
    const float* bo   = (const float*)d_in[14];
    float* out = (float*)d_out;

    float* ws   = (float*)d_ws;
    float* xp   = ws;                                   // NT*NB*NH
    float* xw   = xp  + (size_t)NT * NB * NH;           // NT*NB*3NH
    float* uax  = xw  + (size_t)NT * NB * 3 * NH;       // NT*NB*NH
    float* outs = uax + (size_t)NT * NB * NH;           // NB*NT*NH

    hipLaunchKernelGGL(k_lin_in, dim3(NT * NB), dim3(256), 0, stream, x, W_in, b_in, xp);
    hipLaunchKernelGGL(k_proj,   dim3(NT * NB), dim3(256), 0, stream, xp, Wih, bih, Ua, ub, xw, uax);
    hipLaunchKernelGGL(k_main,   dim3(NB),      dim3(256), 0, stream,
                       Whh, bhh, Wa, ba, va_w, Wo, bo, xp, xw, uax, outs, out);
}

// Round 2
// 167186.401 us; speedup vs baseline: 1.2218x; 1.2218x over previous
//
#include <hip/hip_runtime.h>

constexpr int NB = 32;    // batch
constexpr int NT = 128;   // time
constexpr int NE = 256;   // embed
constexpr int NH = 256;   // hidden
constexpr int NC = 16;    // classes

typedef _Float16 f16;
typedef f16 f16x2 __attribute__((ext_vector_type(2)));
typedef f16 f16x8 __attribute__((ext_vector_type(8)));

__device__ __forceinline__ float sigmoidf_(float x) {
    return 1.f / (1.f + __expf(-x));
}
__device__ __forceinline__ float tanhf_(float x) {
    x = fminf(fmaxf(x, -15.f), 15.f);
    float e = __expf(-2.f * x);
    return (1.f - e) / (1.f + e);
}
__device__ __forceinline__ float dot4_(float4 a, float4 b) {
    return a.x * b.x + a.y * b.y + a.z * b.z + a.w * b.w;
}
#if __has_builtin(__builtin_amdgcn_fdot2)
__device__ __forceinline__ float fdot2_(f16x2 a, f16x2 b, float c) {
    return __builtin_amdgcn_fdot2(a, b, c, false);
}
#else
__device__ __forceinline__ float fdot2_(f16x2 a, f16x2 b, float c) {
    return (float)a[0] * (float)b[0] + (float)a[1] * (float)b[1] + c;
}
#endif
#define PAIR(v, k) __builtin_shufflevector((v), (v), (k), (k) + 1)

// ---------------- Prologue 1: xp[t][b][j] = x[b][t][:] . W_in[j][:] + b_in[j]
__global__ __launch_bounds__(256) void k_lin_in(
    const float* __restrict__ x, const float* __restrict__ W_in,
    const float* __restrict__ b_in, float* __restrict__ xp) {
    const int tb = blockIdx.x;           // t*NB + b
    const int t = tb >> 5, b = tb & 31;
    const int tid = threadIdx.x;
    __shared__ __align__(16) float xl[NE];
    xl[tid] = x[(b * NT + t) * NE + tid];
    __syncthreads();
    const float* __restrict__ wr = W_in + tid * NE;
    float acc = b_in[tid];
#pragma unroll 8
    for (int k = 0; k < NE; k += 4)
        acc += dot4_(*(const float4*)(wr + k), *(const float4*)(xl + k));
    xp[tb * NH + tid] = acc;
}

// ---------------- Prologue 2: xw = xp.Wih^T + bih ; uax = xp.Ua^T + ub
__global__ __launch_bounds__(256) void k_proj(
    const float* __restrict__ xp, const float* __restrict__ Wih,
    const float* __restrict__ bih, const float* __restrict__ Ua,
    const float* __restrict__ ub, float* __restrict__ xw,
    float* __restrict__ uax) {
    const int tb = blockIdx.x;
    const int tid = threadIdx.x;
    __shared__ __align__(16) float xl[NH];
    xl[tid] = xp[tb * NH + tid];
    __syncthreads();
    const float* __restrict__ wr = Wih + tid * NH;
    const float* __restrict__ wz = Wih + (NH + tid) * NH;
    const float* __restrict__ wn = Wih + (2 * NH + tid) * NH;
    const float* __restrict__ wu = Ua + tid * NH;
    float ar = bih[tid], az = bih[NH + tid], an = bih[2 * NH + tid], au = ub[tid];
#pragma unroll 4
    for (int k = 0; k < NH; k += 4) {
        float4 xv = *(const float4*)(xl + k);
        ar += dot4_(*(const float4*)(wr + k), xv);
        az += dot4_(*(const float4*)(wz + k), xv);
        an += dot4_(*(const float4*)(wn + k), xv);
        au += dot4_(*(const float4*)(wu + k), xv);
    }
    float* xwp = xw + tb * (3 * NH);
    xwp[tid] = ar;
    xwp[NH + tid] = az;
    xwp[2 * NH + tid] = an;
    uax[tb * NH + tid] = au;
}

// ---------------- Main: 1 WG / batch element. Whh fp16 in VGPRs, Wa fp16 in LDS.
__global__ __launch_bounds__(512, 2) void k_main(
    const float* __restrict__ Whh, const float* __restrict__ bhh,
    const float* __restrict__ Wa, const float* __restrict__ ba,
    const float* __restrict__ va_w, const float* __restrict__ Wo,
    const float* __restrict__ bo, const float* __restrict__ xp,
    const float* __restrict__ xw, const float* __restrict__ uax,
    f16* __restrict__ outsW, float* __restrict__ out) {
    const int b = blockIdx.x;
    const int tid = threadIdx.x;
    const int lane = tid & 63, wid = tid >> 6;
    const int j = tid >> 1, c = tid & 1;   // output row j, k-chunk c (128 wide)

    // Wa rows padded to 132 pairs (528 B) so consecutive j shift banks by 4.
    __shared__ __align__(16) f16x2 WaH[NH * 132];          // 132 KB
    __shared__ __align__(16) f16 hbuf[2][NH];
    __shared__ float hlast[NH];
    __shared__ float scores[NT], wsm[NT];
    __shared__ float redA[8][4];
    __shared__ float redo[4 * NC];

    // ---- persist Whh (fp16) in registers: 3 gates x 64 f16x2 = 192 VGPRs
    f16x2 wr[64], wz[64], wn[64];
    {
        const float2* pr = (const float2*)(Whh + (0 * NH + j) * NH + c * 128);
        const float2* pz = (const float2*)(Whh + (1 * NH + j) * NH + c * 128);
        const float2* pn = (const float2*)(Whh + (2 * NH + j) * NH + c * 128);
#pragma unroll
        for (int m = 0; m < 64; ++m) {
            float2 a = pr[m]; wr[m] = f16x2{(f16)a.x, (f16)a.y};
            float2 d = pz[m]; wz[m] = f16x2{(f16)d.x, (f16)d.y};
            float2 e = pn[m]; wn[m] = f16x2{(f16)e.x, (f16)e.y};
        }
    }
    // ---- stage Wa into LDS as fp16 pairs
    for (int e = tid; e < NH * 128; e += 512) {
        const int jj = e >> 7, kp = e & 127;
        const float2 v = *(const float2*)(Wa + jj * NH + kp * 2);
        WaH[jj * 132 + kp] = f16x2{(f16)v.x, (f16)v.y};
    }
    if (tid < NH) hbuf[0][tid] = (f16)0.f;

    const float bhr = bhh[j], bhz = bhh[NH + j], bhn = bhh[2 * NH + j];
    const float ba_j = ba[j], va_j = va_w[j];
    f16* __restrict__ ob = outsW + (size_t)b * NT * NH;
    const float* __restrict__ xpB = xp + b * NH;
    const float* __restrict__ uaxB = uax + b * NH;
    float hprev = 0.f;
    int cur = 0;
    __syncthreads();

    for (int i = 0; i < NT; ++i) {
        // ======== GRU chain over prefix t = 0..i (carried hidden) ========
        for (int t = 0; t <= i; ++t) {
            const float* __restrict__ xwp = xw + (size_t)(t * NB + b) * (3 * NH);
            const float xr = xwp[j], xz = xwp[NH + j], xn = xwp[2 * NH + j];
            const f16* hc = hbuf[cur] + c * 128;
            float ar = 0.f, az = 0.f, an = 0.f;
#pragma unroll
            for (int q = 0; q < 16; ++q) {
                const f16x8 hv = *(const f16x8*)(hc + q * 8);
                const f16x2 h0 = PAIR(hv, 0), h1 = PAIR(hv, 2),
                            h2 = PAIR(hv, 4), h3 = PAIR(hv, 6);
                ar = fdot2_(wr[q * 4 + 0], h0, ar);
                ar = fdot2_(wr[q * 4 + 1], h1, ar);
                ar = fdot2_(wr[q * 4 + 2], h2, ar);
                ar = fdot2_(wr[q * 4 + 3], h3, ar);
                az = fdot2_(wz[q * 4 + 0], h0, az);
                az = fdot2_(wz[q * 4 + 1], h1, az);
                az = fdot2_(wz[q * 4 + 2], h2, az);
                az = fdot2_(wz[q * 4 + 3], h3, az);
                an = fdot2_(wn[q * 4 + 0], h0, an);
                an = fdot2_(wn[q * 4 + 1], h1, an);
                an = fdot2_(wn[q * 4 + 2], h2, an);
                an = fdot2_(wn[q * 4 + 3], h3, an);
            }
            ar += __shfl_xor(ar, 1);
            az += __shfl_xor(az, 1);
            an += __shfl_xor(an, 1);
            const float r = sigmoidf_(xr + ar + bhr);
            const float z = sigmoidf_(xz + az + bhz);
            const float n = tanhf_(xn + r * (an + bhn));
            const float hnew = (1.f - z) * n + z * hprev;
            hprev = hnew;
            if (c) {
                hbuf[cur ^ 1][j] = (f16)hnew;
            } else {
                ob[t * NH + j] = (f16)hnew;
                if (t == i) hlast[j] = hnew;
            }
            cur ^= 1;
            __syncthreads();
        }
        __threadfence_block();

        // ======== attention scores for t = 0..i (4 rows per pass) ========
        for (int t0 = 0; t0 <= i; t0 += 4) {
            const f16x2* wrow = WaH + j * 132 + c * 64;
            const f16x8* op[4];
#pragma unroll
            for (int tt = 0; tt < 4; ++tt)
                op[tt] = (const f16x8*)(ob + (t0 + tt) * NH + c * 128);
            float acc[4] = {0.f, 0.f, 0.f, 0.f};
#pragma unroll
            for (int q = 0; q < 16; ++q) {
                const f16x8 wv = *(const f16x8*)(wrow + q * 4);
                const f16x2 w0 = PAIR(wv, 0), w1 = PAIR(wv, 2),
                            w2 = PAIR(wv, 4), w3 = PAIR(wv, 6);
#pragma unroll
                for (int tt = 0; tt < 4; ++tt) {
                    const f16x8 v = op[tt][q];
                    acc[tt] = fdot2_(w0, PAIR(v, 0), acc[tt]);
                    acc[tt] = fdot2_(w1, PAIR(v, 2), acc[tt]);
                    acc[tt] = fdot2_(w2, PAIR(v, 4), acc[tt]);
                    acc[tt] = fdot2_(w3, PAIR(v, 6), acc[tt]);
                }
            }
#pragma unroll
            for (int tt = 0; tt < 4; ++tt) {
                float s = acc[tt];
                s += __shfl_xor(s, 1);
                const float sv = s + ba_j + uaxB[(size_t)(t0 + tt) * NB * NH + j];
                float contrib = (c == 0) ? va_j * tanhf_(sv) : 0.f;
#pragma unroll
                for (int off = 32; off; off >>= 1) contrib += __shfl_xor(contrib, off);
                if (lane == 0) redA[wid][tt] = contrib;
            }
            __syncthreads();
            if (tid < 4) {
                float s = 0.f;
#pragma unroll
                for (int w = 0; w < 8; ++w) s += redA[w][tid];
                scores[t0 + tid] = s;
            }
            __syncthreads();
        }

        // ======== softmax over t = 0..i (va_b cancels) ========
        if (tid < 64) {
            float s1 = (tid <= i) ? scores[tid] : -1e30f;
            float s2 = (64 + tid <= i) ? scores[64 + tid] : -1e30f;
            float m = fmaxf(s1, s2);
#pragma unroll
            for (int off = 32; off; off >>= 1) m = fmaxf(m, __shfl_xor(m, off));
            float e1 = (tid <= i) ? __expf(s1 - m) : 0.f;
            float e2 = (64 + tid <= i) ? __expf(s2 - m) : 0.f;
            float ssum = e1 + e2;
#pragma unroll
            for (int off = 32; off; off >>= 1) ssum += __shfl_xor(ssum, off);
            const float inv = 1.f / ssum;
            wsm[tid] = e1 * inv;
            wsm[64 + tid] = e2 * inv;
        }
        __syncthreads();

        // ======== context + output head (waves 0-3) ========
        if (tid < NH) {
            float ctx = 0.f;
            for (int t = 0; t <= i; ++t) ctx += wsm[t] * xpB[(size_t)t * NB * NH + tid];
            const float hl = hlast[tid];
#pragma unroll
            for (int cc = 0; cc < NC; ++cc) {
                float p = Wo[cc * (2 * NH) + tid] * hl + Wo[cc * (2 * NH) + NH + tid] * ctx;
#pragma unroll
                for (int off = 32; off; off >>= 1) p += __shfl_xor(p, off);
                if (lane == 0) redo[wid * NC + cc] = p;
            }
        }
        __syncthreads();
        if (tid < NC) {
            const float lg = redo[tid] + redo[NC + tid] + redo[2 * NC + tid] +
                             redo[3 * NC + tid] + bo[tid];
            out[((size_t)b * NT + i) * NC + tid] = sigmoidf_(lg);
        }
        __syncthreads();
    }
}

extern "C" void kernel_launch(void* const* d_in, const int* in_sizes, int n_in,
                              void* d_out, int out_size, void* d_ws, size_t ws_size,
                              hipStream_t stream) {
    (void)in_sizes; (void)n_in; (void)out_size; (void)ws_size;
    const float* x    = (const float*)d_in[0];
    const float* W_in = (const float*)d_in[1];
    const float* b_in = (const float*)d_in[2];
    const float* Wih  = (const float*)d_in[3];
    const float* bih  = (const float*)d_in[4];
    const float* Whh  = (const float*)d_in[5];
    const float* bhh  = (const float*)d_in[6];
    const float* Wa   = (const float*)d_in[7];
    const float* ba   = (const float*)d_in[8];
    const float* Ua   = (const float*)d_in[9];
    const float* ub   = (const float*)d_in[10];
    const float* va_w = (const float*)d_in[11];
    // d_in[12] = va_b: cancels in softmax
    const float* Wo   = (const float*)d_in[13];
    const float* bo   = (const float*)d_in[14];
    float* out = (float*)d_out;

    float* ws   = (float*)d_ws;
    float* xp   = ws;                                   // NT*NB*NH floats
    float* xw   = xp  + (size_t)NT * NB * NH;           // NT*NB*3NH floats
    float* uax  = xw  + (size_t)NT * NB * 3 * NH;       // NT*NB*NH floats
    f16*   outsW = (f16*)(uax + (size_t)NT * NB * NH);  // NB*NT*NH halves

    hipLaunchKernelGGL(k_lin_in, dim3(NT * NB), dim3(256), 0, stream, x, W_in, b_in, xp);
    hipLaunchKernelGGL(k_proj,   dim3(NT * NB), dim3(256), 0, stream, xp, Wih, bih, Ua, ub, xw, uax);
    hipLaunchKernelGGL(k_main,   dim3(NB),      dim3(512), 0, stream,
                       Whh, bhh, Wa, ba, va_w, Wo, bo, xp, xw, uax, outsW, out);
}